// Round 11
// baseline (1225.200 us; speedup 1.0000x reference)
//
#include <hip/hip_runtime.h>

#define N_NODES 256
#define COND    64
#define E_PAIRS 32640
#define OUTCOLS 65280
#define BATCH   512
#define SLOTS   576    // 9 row-tiles of 64 (big rows padded to 64, then small, then pad)
#define D1      256
#define D2      512
#define D3      1024
#define COLCAP  16384  // limb-buffer col capacity per phase (128 col-tiles)
// u32 strides inside limb buffer: [t][limb][col][16 u32]
#define LSTRU   (COLCAP * 16)          // 262144 u32
#define TSTRU   (3 * COLCAP * 16)      // 786432 u32

typedef __attribute__((ext_vector_type(8))) short bf16x8;   // MFMA A/B frag (4 VGPR)
typedef __attribute__((ext_vector_type(4))) float f32x4;    // MFMA C/D frag
typedef __attribute__((ext_vector_type(4))) unsigned int u32x4;

static __device__ __forceinline__ unsigned short f2bf(float f) {   // RNE float->bf16
    unsigned int u = __float_as_uint(f);
    u += 0x7FFF + ((u >> 16) & 1);
    return (unsigned short)(u >> 16);
}
static __device__ __forceinline__ float bf2f(unsigned short h) {
    return __uint_as_float(((unsigned int)h) << 16);
}

// ---------------- kernel 0: ballot-based stable sort into 64-aligned slots ---
__global__ void k0_sort(const float* __restrict__ x, int* __restrict__ meta,
                        int* __restrict__ borig) {
    __shared__ int wc[9];
    int t = threadIdx.x;                 // blockDim = 576 (9 waves)
    if (t < SLOTS) borig[t] = -1;        // pad default
    int m = 0;
    if (t < BATCH) m = (x[t * COND] > 0.0f) ? 1 : 0;
    unsigned long long bm = __ballot(m);
    int wave = t >> 6;
    int lane = t & 63;
    int lanePre = __popcll(bm & ((1ull << lane) - 1ull));
    if (lane == 0) wc[wave] = __popcll(bm);
    __syncthreads();
    int nbig = 0, preBig = 0;
    #pragma unroll
    for (int w = 0; w < 8; ++w) {        // waves 0..7 cover t<512
        int c = wc[w];
        if (w < wave) preBig += c;
        nbig += c;
    }
    int S = (nbig + 63) & ~63;           // big slots [0,S), small [S, S+nsmall)
    if (t < BATCH) {
        int onesBefore = preBig + lanePre;
        int slot = m ? onesBefore : (S + (t - onesBefore));
        borig[slot] = t;
    }
    if (t == 0) meta[0] = S;
}

// ---------------- kernel 1: MLP layers as tiled GEMMs ------------------------
// 64x64 tile, 256 threads, 4x4 per thread, ReLU fused.
// GATHER (layer 0): rows via borig. SPLIT (layer 2): write h as 3 bf16 limbs
// DIRECTLY IN MFMA A-FRAGMENT LANE ORDER (hbA) so k2 loads coalesced frags.
template <bool GATHER, int K, int DOUT, bool SPLIT>
__global__ __launch_bounds__(256) void k1_gemm(
    const float* __restrict__ in,
    const float* __restrict__ wbig, const float* __restrict__ bbig,
    const float* __restrict__ wsml, const float* __restrict__ bsml,
    const int* __restrict__ meta, const int* __restrict__ borig,
    float* __restrict__ out, unsigned short* __restrict__ hbA) {
    __shared__ float hs[16][64 + 4];     // transposed act tile
    __shared__ float wt[16][64 + 4];     // weight tile
    int tid = threadIdx.x;
    int by = blockIdx.x;                 // row tile 0..8
    int bx = blockIdx.y;                 // col tile
    int r0 = by * 64;
    int cb = bx * 64;
    int S = meta[0];
    bool big = (r0 < S);                 // row tiles are expert-uniform
    const float* w = big ? wbig : wsml;
    const float* bias = big ? bbig : bsml;

    int lm = tid >> 2;                   // act-load row 0..63
    int lq = tid & 3;                    // act-load k quad
    int wk = tid >> 4;                   // w-load k row 0..15
    int wc = (tid & 15) * 4;             // w-load col offset

    int tm = tid >> 4;                   // 0..15 : rows tm*4..+3
    int tn = tid & 15;                   // 0..15 : cols tn*4..+3

    const float* hrow;
    if (GATHER) {
        int b = borig[r0 + lm];
        hrow = (b >= 0) ? &in[(size_t)b * K] : (const float*)0;
    } else {
        hrow = &in[(size_t)(r0 + lm) * K];   // pad rows hold garbage; harmless
    }

    float acc[4][4];
    #pragma unroll
    for (int i = 0; i < 4; ++i)
        #pragma unroll
        for (int j = 0; j < 4; ++j) acc[i][j] = 0.f;

    for (int k0 = 0; k0 < K; k0 += 16) {
        float4 hv = make_float4(0.f, 0.f, 0.f, 0.f);
        if (!GATHER || hrow) hv = *(const float4*)&hrow[k0 + lq * 4];
        float4 wv = *(const float4*)&w[(size_t)(k0 + wk) * DOUT + cb + wc];
        __syncthreads();
        hs[lq * 4 + 0][lm] = hv.x;
        hs[lq * 4 + 1][lm] = hv.y;
        hs[lq * 4 + 2][lm] = hv.z;
        hs[lq * 4 + 3][lm] = hv.w;
        *(float4*)&wt[wk][wc] = wv;
        __syncthreads();
        #pragma unroll
        for (int kk = 0; kk < 16; ++kk) {
            float4 a  = *(const float4*)&hs[kk][tm * 4];
            float4 bf = *(const float4*)&wt[kk][tn * 4];
            acc[0][0] = fmaf(a.x, bf.x, acc[0][0]);
            acc[0][1] = fmaf(a.x, bf.y, acc[0][1]);
            acc[0][2] = fmaf(a.x, bf.z, acc[0][2]);
            acc[0][3] = fmaf(a.x, bf.w, acc[0][3]);
            acc[1][0] = fmaf(a.y, bf.x, acc[1][0]);
            acc[1][1] = fmaf(a.y, bf.y, acc[1][1]);
            acc[1][2] = fmaf(a.y, bf.z, acc[1][2]);
            acc[1][3] = fmaf(a.y, bf.w, acc[1][3]);
            acc[2][0] = fmaf(a.z, bf.x, acc[2][0]);
            acc[2][1] = fmaf(a.z, bf.y, acc[2][1]);
            acc[2][2] = fmaf(a.z, bf.z, acc[2][2]);
            acc[2][3] = fmaf(a.z, bf.w, acc[2][3]);
            acc[3][0] = fmaf(a.w, bf.x, acc[3][0]);
            acc[3][1] = fmaf(a.w, bf.y, acc[3][1]);
            acc[3][2] = fmaf(a.w, bf.z, acc[3][2]);
            acc[3][3] = fmaf(a.w, bf.w, acc[3][3]);
        }
    }

    float4 bv = *(const float4*)&bias[cb + tn * 4];
    #pragma unroll
    for (int i = 0; i < 4; ++i) {
        float o[4];
        o[0] = fmaxf(acc[i][0] + bv.x, 0.f);
        o[1] = fmaxf(acc[i][1] + bv.y, 0.f);
        o[2] = fmaxf(acc[i][2] + bv.z, 0.f);
        o[3] = fmaxf(acc[i][3] + bv.w, 0.f);
        if (SPLIT) {
            // element (row, k): frag addr = ((by*32+kk)*3+limb)*2048 + m*512
            //                               + (lg*16 + l15)*8 + j   [shorts]
            int row = r0 + tm * 4 + i;
            int by_ = row >> 6, rl = row & 63;
            int mfr = rl >> 4, p15 = rl & 15;
            int kt  = cb + tn * 4;           // 4 consecutive k, same lg group
            int kk  = kt >> 5, lgk = (kt >> 3) & 3, j0 = kt & 7;
            size_t base = (size_t)(by_ * 32 + kk) * 6144 + (size_t)mfr * 512
                        + (size_t)(lgk * 16 + p15) * 8 + j0;
            ushort4 s0, s1, s2;
            unsigned short* q0[4] = {&s0.x, &s0.y, &s0.z, &s0.w};
            unsigned short* q1[4] = {&s1.x, &s1.y, &s1.z, &s1.w};
            unsigned short* q2[4] = {&s2.x, &s2.y, &s2.z, &s2.w};
            #pragma unroll
            for (int j = 0; j < 4; ++j) {
                unsigned short a0 = f2bf(o[j]);
                float r1v = o[j] - bf2f(a0);
                unsigned short a1 = f2bf(r1v);
                float r2v = r1v - bf2f(a1);
                *q0[j] = a0; *q1[j] = a1; *q2[j] = f2bf(r2v);
            }
            *(ushort4*)&hbA[base]        = s0;
            *(ushort4*)&hbA[base + 2048] = s1;
            *(ushort4*)&hbA[base + 4096] = s2;
        } else {
            float4 ov;
            ov.x = o[0]; ov.y = o[1]; ov.z = o[2]; ov.w = o[3];
            *(float4*)&out[(size_t)(r0 + tm * 4 + i) * DOUT + cb + tn * 4] = ov;
        }
    }
}

// ---------------- prepass: w3 diff + 3-limb split, B-fragment packed ---------
// Streams w3 CONTIGUOUSLY (the pattern HBM runs at ~5 TB/s) and writes limbs
// in exact MFMA B-frag order: [t][limb][col][32k as 64 B]. k2's strided
// float2 gather + per-step split VALU both disappear. One expert x one
// col-half per launch (buffer 100.7 MB -> written & re-read L3-hot).
__global__ __launch_bounds__(256) void kp_split(
    const float* __restrict__ w3, unsigned int* __restrict__ bb,
    int colsBase, int ncols) {
    int tid = threadIdx.x;
    int cx = blockIdx.x;                // 0..63
    int t  = blockIdx.y;                // 0..31 (K-tile)
    int c  = cx * 256 + tid;            // phase-local diff col
    if (c >= ncols) return;
    const float* wp = w3 + (size_t)(t * 32) * OUTCOLS + 2 * (size_t)(colsBase + c);
    unsigned int L0[16], L1[16], L2[16];
    #pragma unroll
    for (int kk = 0; kk < 32; kk += 2) {
        float2 a = *(const float2*)(wp + (size_t)kk * OUTCOLS);
        float2 b = *(const float2*)(wp + (size_t)(kk + 1) * OUTCOLS);
        float dA = a.x - a.y, dB = b.x - b.y;
        unsigned short aL = f2bf(dA), aH = f2bf(dB);
        L0[kk >> 1] = (unsigned)aL | ((unsigned)aH << 16);
        float rA = dA - bf2f(aL), rB = dB - bf2f(aH);
        unsigned short bL = f2bf(rA), bH = f2bf(rB);
        L1[kk >> 1] = (unsigned)bL | ((unsigned)bH << 16);
        float sA = rA - bf2f(bL), sB = rB - bf2f(bH);
        L2[kk >> 1] = (unsigned)f2bf(sA) | ((unsigned)f2bf(sB) << 16);
    }
    unsigned int* p = bb + (size_t)t * TSTRU + (size_t)c * 16;
    #pragma unroll
    for (int i = 0; i < 4; ++i) {
        u32x4 v0 = {L0[4*i], L0[4*i+1], L0[4*i+2], L0[4*i+3]};
        u32x4 v1 = {L1[4*i], L1[4*i+1], L1[4*i+2], L1[4*i+3]};
        u32x4 v2 = {L2[4*i], L2[4*i+1], L2[4*i+2], L2[4*i+3]};
        *(u32x4*)(p + i * 4)             = v0;
        *(u32x4*)(p + LSTRU + i * 4)     = v1;
        *(u32x4*)(p + 2 * LSTRU + i * 4) = v2;
    }
}

// ---------------- kernel 2 (pre path): pure fragment-load + MFMA -------------
// Per step: 12 A-frag + 6 B-frag dwordx4 loads (L2/L3-hot) + 48 MFMA.
// No split VALU, no strided gathers. Inputs bit-identical to the proven
// R6/R7 MFMA stream (same diff/limb math, computed in kp_split).
// Grid 1152, XCD-contiguous col ownership; expert selected by phase.
template <bool BIGPHASE>
__global__ __launch_bounds__(256) void k2p(
    const unsigned short* __restrict__ hbA, const unsigned int* __restrict__ bb,
    const float* __restrict__ bb3, const float* __restrict__ sb3,
    const float* __restrict__ gum, const int* __restrict__ meta,
    const int* __restrict__ borig, unsigned char* __restrict__ bits,
    int ctBase, int ntiles) {
    int tid = threadIdx.x;
    int wgid = blockIdx.x;              // 0..1151
    int xr = wgid & 7;                  // XCD slot
    int s_ = wgid >> 3;                 // 0..143
    int unit = xr * 144 + s_;           // XCD xr owns contiguous unit range
    if (unit >= 9 * ntiles) return;
    int ct = unit / 9;                  // phase-local col tile (by-inner order)
    int by = unit % 9;
    int S = meta[0];
    bool big = (by * 64 < S);
    if (big != BIGPHASE) return;        // other expert's phase; no barriers -> safe
    int r0 = by * 64;

    int lane = tid & 63;
    int wid  = tid >> 6;                // wave 0..3 -> diff cols wid*32..+31
    int l15  = lane & 15;
    int lg   = lane >> 4;               // k-group 0..3

    int lc    = ct * 128 + wid * 32 + l15;       // phase-local col (n=0)
    int colg0 = ctBase * 128 + lc;               // global diff col (n=0)

    f32x4 acc[4][2];
    #pragma unroll
    for (int m = 0; m < 4; ++m)
        #pragma unroll
        for (int n = 0; n < 2; ++n) acc[m][n] = (f32x4)0.f;

    const unsigned short* ap0 = hbA + (size_t)(by * 32) * 6144 + (size_t)lane * 8;
    const unsigned int*   bp0 = bb + (size_t)lc * 16 + lg * 4;

    for (int t = 0; t < 32; ++t) {
        const unsigned short* ap = ap0 + (size_t)t * 6144;
        bf16x8 af[3][4];
        #pragma unroll
        for (int l = 0; l < 3; ++l)
            #pragma unroll
            for (int m = 0; m < 4; ++m)
                af[l][m] = *(const bf16x8*)(ap + l * 2048 + m * 512);
        const unsigned int* bp = bp0 + (size_t)t * TSTRU;
        #pragma unroll
        for (int n = 0; n < 2; ++n) {
            bf16x8 b0 = __builtin_bit_cast(bf16x8, *(const u32x4*)(bp + n * 256));
            bf16x8 b1 = __builtin_bit_cast(bf16x8, *(const u32x4*)(bp + LSTRU + n * 256));
            bf16x8 b2 = __builtin_bit_cast(bf16x8, *(const u32x4*)(bp + 2 * LSTRU + n * 256));
            #pragma unroll
            for (int m = 0; m < 4; ++m) {
                f32x4 c = acc[m][n];
                c = __builtin_amdgcn_mfma_f32_16x16x32_bf16(af[0][m], b0, c, 0, 0, 0);
                c = __builtin_amdgcn_mfma_f32_16x16x32_bf16(af[0][m], b1, c, 0, 0, 0);
                c = __builtin_amdgcn_mfma_f32_16x16x32_bf16(af[1][m], b0, c, 0, 0, 0);
                c = __builtin_amdgcn_mfma_f32_16x16x32_bf16(af[1][m], b1, c, 0, 0, 0);
                c = __builtin_amdgcn_mfma_f32_16x16x32_bf16(af[0][m], b2, c, 0, 0, 0);
                c = __builtin_amdgcn_mfma_f32_16x16x32_bf16(af[2][m], b0, c, 0, 0, 0);
                acc[m][n] = c;
            }
        }
    }

    const float* b3 = BIGPHASE ? bb3 : sb3;
    #pragma unroll
    for (int n = 0; n < 2; ++n) {
        int colg = colg0 + n * 16;
        float2 bv = *(const float2*)&b3[2 * colg];
        float bd = bv.x - bv.y;
        #pragma unroll
        for (int m = 0; m < 4; ++m) {
            #pragma unroll
            for (int r = 0; r < 4; ++r) {
                int slot = r0 + m * 16 + lg * 4 + r;
                int b = borig[slot];
                if (b < 0) continue;
                float2 gv = *(const float2*)&gum[(size_t)b * OUTCOLS + 2 * colg];
                float g = acc[m][n][r] + bd + (gv.x - gv.y);
                bits[(size_t)b * E_PAIRS + colg] = (g >= 0.f) ? 1 : 0;
            }
        }
    }
}

// ---------------- kernel 2 (fallback, R7 proven 455us): in-register split ----
__global__ __launch_bounds__(256, 3) void k2_fb(
    const unsigned short* __restrict__ hbA,
    const float* __restrict__ bw3, const float* __restrict__ bb3,
    const float* __restrict__ sw3, const float* __restrict__ sb3,
    const float* __restrict__ gum,
    const int* __restrict__ meta, const int* __restrict__ borig,
    unsigned char* __restrict__ bits) {
    int tid = threadIdx.x;
    int wgid = blockIdx.x;              // 0..2303
    int xr  = wgid & 7;
    int s_  = wgid >> 3;
    int by  = s_ % 9;
    int q   = s_ / 9;
    int bx  = q * 8 + xr;
    if (bx >= 255) return;

    int r0 = by * 64;
    int db = bx * 128;
    int S = meta[0];
    bool big = (r0 < S);
    const float* w3 = big ? bw3 : sw3;
    const float* b3 = big ? bb3 : sb3;

    int lane = tid & 63;
    int wid  = tid >> 6;
    int l15  = lane & 15;
    int lg   = lane >> 4;
    int colg0 = db + wid * 32 + l15;

    f32x4 acc[4][2];
    #pragma unroll
    for (int m = 0; m < 4; ++m)
        #pragma unroll
        for (int n = 0; n < 2; ++n) acc[m][n] = (f32x4)0.f;

    const unsigned short* ap0 = hbA + (size_t)(by * 32) * 6144 + (size_t)lane * 8;
    const float* wbase = w3 + (size_t)(lg * 8) * OUTCOLS + 2 * (size_t)colg0;

#define LOADB(BUF, KK) do {                                                     \
    const float* wp_ = wbase + (size_t)(KK) * 32 * OUTCOLS;                     \
    _Pragma("unroll")                                                           \
    for (int n_ = 0; n_ < 2; ++n_) {                                            \
        _Pragma("unroll")                                                       \
        for (int j_ = 0; j_ < 8; ++j_)                                          \
            BUF[n_ * 8 + j_] = *(const float2*)(wp_ + (size_t)j_ * OUTCOLS      \
                                                + n_ * 32);                     \
    }                                                                           \
} while (0)

#define STEP(BUF, KK) do {                                                      \
    const unsigned short* ap_ = ap0 + (size_t)(KK) * 6144;                      \
    bf16x8 af_[3][4];                                                           \
    _Pragma("unroll")                                                           \
    for (int l_ = 0; l_ < 3; ++l_)                                              \
        _Pragma("unroll")                                                       \
        for (int m_ = 0; m_ < 4; ++m_)                                          \
            af_[l_][m_] = *(const bf16x8*)(ap_ + l_ * 2048 + m_ * 512);         \
    _Pragma("unroll")                                                           \
    for (int n_ = 0; n_ < 2; ++n_) {                                            \
        u32x4 f0_, f1_, f2_;                                                    \
        _Pragma("unroll")                                                       \
        for (int w_ = 0; w_ < 4; ++w_) {                                        \
            float dA_ = BUF[n_ * 8 + 2 * w_].x     - BUF[n_ * 8 + 2 * w_].y;    \
            float dB_ = BUF[n_ * 8 + 2 * w_ + 1].x - BUF[n_ * 8 + 2 * w_ + 1].y;\
            unsigned short aL_ = f2bf(dA_), aH_ = f2bf(dB_);                    \
            f0_[w_] = (unsigned int)aL_ | ((unsigned int)aH_ << 16);            \
            float rA_ = dA_ - bf2f(aL_), rB_ = dB_ - bf2f(aH_);                 \
            unsigned short bL_ = f2bf(rA_), bH_ = f2bf(rB_);                    \
            f1_[w_] = (unsigned int)bL_ | ((unsigned int)bH_ << 16);            \
            float sA_ = rA_ - bf2f(bL_), sB_ = rB_ - bf2f(bH_);                 \
            f2_[w_] = (unsigned int)f2bf(sA_) | ((unsigned int)f2bf(sB_) << 16);\
        }                                                                       \
        bf16x8 b0_ = __builtin_bit_cast(bf16x8, f0_);                           \
        bf16x8 b1_ = __builtin_bit_cast(bf16x8, f1_);                           \
        bf16x8 b2_ = __builtin_bit_cast(bf16x8, f2_);                           \
        _Pragma("unroll")                                                       \
        for (int m_ = 0; m_ < 4; ++m_) {                                        \
            f32x4 c_ = acc[m_][n_];                                             \
            c_ = __builtin_amdgcn_mfma_f32_16x16x32_bf16(af_[0][m_], b0_, c_, 0, 0, 0); \
            c_ = __builtin_amdgcn_mfma_f32_16x16x32_bf16(af_[0][m_], b1_, c_, 0, 0, 0); \
            c_ = __builtin_amdgcn_mfma_f32_16x16x32_bf16(af_[1][m_], b0_, c_, 0, 0, 0); \
            c_ = __builtin_amdgcn_mfma_f32_16x16x32_bf16(af_[1][m_], b1_, c_, 0, 0, 0); \
            c_ = __builtin_amdgcn_mfma_f32_16x16x32_bf16(af_[0][m_], b2_, c_, 0, 0, 0); \
            c_ = __builtin_amdgcn_mfma_f32_16x16x32_bf16(af_[2][m_], b0_, c_, 0, 0, 0); \
            acc[m_][n_] = c_;                                                   \
        }                                                                       \
    }                                                                           \
} while (0)

    float2 brE[16], brO[16];
    LOADB(brE, 0);
    for (int ki = 0; ki < 16; ++ki) {
        int ke = ki * 2;
        LOADB(brO, ke + 1);
        STEP(brE, ke);
        LOADB(brE, (ki < 15) ? ke + 2 : 31);
        STEP(brO, ke + 1);
    }
#undef LOADB
#undef STEP

    #pragma unroll
    for (int n = 0; n < 2; ++n) {
        int colg = db + wid * 32 + n * 16 + l15;
        float2 bv = *(const float2*)&b3[2 * colg];
        float bd = bv.x - bv.y;
        #pragma unroll
        for (int m = 0; m < 4; ++m) {
            #pragma unroll
            for (int r = 0; r < 4; ++r) {
                int slot = r0 + m * 16 + lg * 4 + r;
                int b = borig[slot];
                if (b < 0) continue;
                float2 gv = *(const float2*)&gum[(size_t)b * OUTCOLS + 2 * colg];
                float g = acc[m][n][r] + bd + (gv.x - gv.y);
                bits[(size_t)b * E_PAIRS + colg] = (g >= 0.f) ? 1 : 0;
            }
        }
    }
}

// ---------------- kernel 3: tiled bit->fp32 expansion with LDS transpose ------
__global__ __launch_bounds__(256) void k3_expand(
    const unsigned char* __restrict__ bits, float* __restrict__ out) {
    __shared__ unsigned char L[64][68];   // stride 68 bytes
    int p = blockIdx.x;                   // 0..9 -> (ti,tj), ti<=tj
    int ti = (p >= 4) + (p >= 7) + (p >= 9);
    int off = (ti == 0) ? 0 : (ti == 1) ? 4 : (ti == 2) ? 7 : 9;
    int tj = ti + (p - off);
    int b = blockIdx.y;                   // 0..511
    int t = threadIdx.x;

    {
        int r = t >> 2;                   // 0..63
        int q = t & 3;                    // 0..3
        int i = ti * 64 + r;
        long base = (long)b * E_PAIRS + (long)i * (511 - i) / 2 - i - 1;
        int j0 = tj * 64 + q * 16;
        #pragma unroll
        for (int k = 0; k < 16; ++k) {
            int j = j0 + k;
            unsigned char v = (j > i) ? bits[base + j] : (unsigned char)0;
            L[r][q * 16 + k] = v;
        }
    }
    __syncthreads();

    int h  = t >> 4;                      // 0..15
    int w4 = (t & 15) * 4;                // col base, float4 granularity

    {
        #pragma unroll
        for (int rr = 0; rr < 4; ++rr) {
            int ii = rr * 16 + h;
            int i_ = ti * 64 + ii;
            float4 v;
            if (ti == tj) {
                int jj;
                jj = w4 + 0; v.x = (jj > ii) ? (float)L[ii][jj] : (jj < ii ? (float)L[jj][ii] : 0.f);
                jj = w4 + 1; v.y = (jj > ii) ? (float)L[ii][jj] : (jj < ii ? (float)L[jj][ii] : 0.f);
                jj = w4 + 2; v.z = (jj > ii) ? (float)L[ii][jj] : (jj < ii ? (float)L[jj][ii] : 0.f);
                jj = w4 + 3; v.w = (jj > ii) ? (float)L[ii][jj] : (jj < ii ? (float)L[jj][ii] : 0.f);
            } else {
                v.x = (float)L[ii][w4 + 0];
                v.y = (float)L[ii][w4 + 1];
                v.z = (float)L[ii][w4 + 2];
                v.w = (float)L[ii][w4 + 3];
            }
            size_t o = (((size_t)b * 256 + i_) * 256) + tj * 64 + w4;
            *(float4*)&out[o] = v;
        }
    }

    if (ti != tj) {
        #pragma unroll
        for (int rr = 0; rr < 4; ++rr) {
            int jj = rr * 16 + h;
            int j_ = tj * 64 + jj;
            float4 v;
            v.x = (float)L[w4 + 0][jj];
            v.y = (float)L[w4 + 1][jj];
            v.z = (float)L[w4 + 2][jj];
            v.w = (float)L[w4 + 3][jj];
            size_t o = (((size_t)b * 256 + j_) * 256) + ti * 64 + w4;
            *(float4*)&out[o] = v;
        }
    }
}

// -----------------------------------------------------------------------------
extern "C" void kernel_launch(void* const* d_in, const int* in_sizes, int n_in,
                              void* d_out, int out_size, void* d_ws, size_t ws_size,
                              hipStream_t stream) {
    const float* x   = (const float*)d_in[0];
    const float* gum = (const float*)d_in[1];
    const float* bw0 = (const float*)d_in[2];  const float* bb0 = (const float*)d_in[3];
    const float* sw0 = (const float*)d_in[4];  const float* sb0 = (const float*)d_in[5];
    const float* bw1 = (const float*)d_in[6];  const float* bb1 = (const float*)d_in[7];
    const float* sw1 = (const float*)d_in[8];  const float* sb1 = (const float*)d_in[9];
    const float* bw2 = (const float*)d_in[10]; const float* bb2 = (const float*)d_in[11];
    const float* sw2 = (const float*)d_in[12]; const float* sb2 = (const float*)d_in[13];
    const float* bw3 = (const float*)d_in[14]; const float* bb3 = (const float*)d_in[15];
    const float* sw3 = (const float*)d_in[16]; const float* sb3 = (const float*)d_in[17];

    char* ws = (char*)d_ws;
    int*   meta  = (int*)ws;                               // 64 B
    int*   borig = (int*)(ws + 64);                        // 576 ints
    float* act1  = (float*)(ws + 4096);                    // 576*256 fp32
    float* act2  = (float*)(ws + 593920);                  // 576*512 fp32
    unsigned short* hbA = (unsigned short*)(ws + 1773568); // 576*1024*3 bf16 frag-order
    unsigned char* bits = (unsigned char*)(ws + 5312512);  // 512*32640 -> ends 22024192
    unsigned int* bb = (unsigned int*)(ws + 22024192);     // limb buffer 100.66 MB
    float* out = (float*)d_out;

    size_t need_pre = 22024192ull + (size_t)32 * TSTRU * 4;   // ~122.7 MB
    bool pre = (ws_size >= need_pre);

    k0_sort<<<1, SLOTS, 0, stream>>>(x, meta, borig);
    k1_gemm<true,  COND, D1, false><<<dim3(9, D1 / 64), 256, 0, stream>>>(
        x,    bw0, bb0, sw0, sb0, meta, borig, act1, 0);
    k1_gemm<false, D1,   D2, false><<<dim3(9, D2 / 64), 256, 0, stream>>>(
        act1, bw1, bb1, sw1, sb1, meta, borig, act2, 0);
    k1_gemm<false, D2,   D3, true><<<dim3(9, D3 / 64), 256, 0, stream>>>(
        act2, bw2, bb2, sw2, sb2, meta, borig, (float*)0, hbA);

    if (pre) {
        // phase: (expert, col-half). Buffer written then read L3-hot.
        // half A: col-tiles [0,128) = cols [0,16384); half B: [128,255) = 16256 cols
        kp_split<<<dim3(64, 32), 256, 0, stream>>>(bw3, bb, 0, 16384);
        k2p<true ><<<1152, 256, 0, stream>>>(hbA, bb, bb3, sb3, gum, meta, borig, bits, 0, 128);
        kp_split<<<dim3(64, 32), 256, 0, stream>>>(sw3, bb, 0, 16384);
        k2p<false><<<1152, 256, 0, stream>>>(hbA, bb, bb3, sb3, gum, meta, borig, bits, 0, 128);
        kp_split<<<dim3(64, 32), 256, 0, stream>>>(bw3, bb, 16384, 16256);
        k2p<true ><<<1152, 256, 0, stream>>>(hbA, bb, bb3, sb3, gum, meta, borig, bits, 128, 127);
        kp_split<<<dim3(64, 32), 256, 0, stream>>>(sw3, bb, 16384, 16256);
        k2p<false><<<1152, 256, 0, stream>>>(hbA, bb, bb3, sb3, gum, meta, borig, bits, 128, 127);
    } else {
        k2_fb<<<2304, 256, 0, stream>>>(hbA, bw3, bb3, sw3, sb3, gum,
                                        meta, borig, bits);
    }
    k3_expand<<<dim3(10, BATCH), 256, 0, stream>>>(bits, out);
}

// Round 12
// 1044.754 us; speedup vs baseline: 1.1727x; 1.1727x over previous
//
#include <hip/hip_runtime.h>

#define N_NODES 256
#define COND    64
#define E_PAIRS 32640
#define OUTCOLS 65280
#define BATCH   512
#define SLOTS   576    // 9 row-tiles of 64 (big rows padded to 64, then small, then pad)
#define D1      256
#define D2      512
#define D3      1024

typedef __attribute__((ext_vector_type(8))) short bf16x8;   // MFMA A/B frag (4 VGPR)
typedef __attribute__((ext_vector_type(4))) float f32x4;    // MFMA C/D frag
typedef __attribute__((ext_vector_type(4))) unsigned int u32x4;

static __device__ __forceinline__ unsigned short f2bf(float f) {   // RNE float->bf16
    unsigned int u = __float_as_uint(f);
    u += 0x7FFF + ((u >> 16) & 1);
    return (unsigned short)(u >> 16);
}
static __device__ __forceinline__ float bf2f(unsigned short h) {
    return __uint_as_float(((unsigned int)h) << 16);
}

// ---------------- kernel 0: ballot-based stable sort into 64-aligned slots ---
__global__ void k0_sort(const float* __restrict__ x, int* __restrict__ meta,
                        int* __restrict__ borig) {
    __shared__ int wc[9];
    int t = threadIdx.x;                 // blockDim = 576 (9 waves)
    if (t < SLOTS) borig[t] = -1;        // pad default
    int m = 0;
    if (t < BATCH) m = (x[t * COND] > 0.0f) ? 1 : 0;
    unsigned long long bm = __ballot(m);
    int wave = t >> 6;
    int lane = t & 63;
    int lanePre = __popcll(bm & ((1ull << lane) - 1ull));
    if (lane == 0) wc[wave] = __popcll(bm);
    __syncthreads();
    int nbig = 0, preBig = 0;
    #pragma unroll
    for (int w = 0; w < 8; ++w) {        // waves 0..7 cover t<512
        int c = wc[w];
        if (w < wave) preBig += c;
        nbig += c;
    }
    int S = (nbig + 63) & ~63;           // big slots [0,S), small [S, S+nsmall)
    if (t < BATCH) {
        int onesBefore = preBig + lanePre;
        int slot = m ? onesBefore : (S + (t - onesBefore));
        borig[slot] = t;
    }
    if (t == 0) meta[0] = S;
}

// ---------------- kernel 1: MLP layers as tiled GEMMs ------------------------
// 64x64 tile, 256 threads, 4x4 per thread, ReLU fused.
// GATHER (layer 0): rows via borig. SPLIT (layer 2): write h as 3 bf16 limbs
// DIRECTLY IN MFMA A-FRAGMENT LANE ORDER (hbA) so k2 loads coalesced frags.
template <bool GATHER, int K, int DOUT, bool SPLIT>
__global__ __launch_bounds__(256) void k1_gemm(
    const float* __restrict__ in,
    const float* __restrict__ wbig, const float* __restrict__ bbig,
    const float* __restrict__ wsml, const float* __restrict__ bsml,
    const int* __restrict__ meta, const int* __restrict__ borig,
    float* __restrict__ out, unsigned short* __restrict__ hbA) {
    __shared__ float hs[16][64 + 4];     // transposed act tile
    __shared__ float wt[16][64 + 4];     // weight tile
    int tid = threadIdx.x;
    int by = blockIdx.x;                 // row tile 0..8
    int bx = blockIdx.y;                 // col tile
    int r0 = by * 64;
    int cb = bx * 64;
    int S = meta[0];
    bool big = (r0 < S);                 // row tiles are expert-uniform
    const float* w = big ? wbig : wsml;
    const float* bias = big ? bbig : bsml;

    int lm = tid >> 2;                   // act-load row 0..63
    int lq = tid & 3;                    // act-load k quad
    int wk = tid >> 4;                   // w-load k row 0..15
    int wc = (tid & 15) * 4;             // w-load col offset

    int tm = tid >> 4;                   // 0..15 : rows tm*4..+3
    int tn = tid & 15;                   // 0..15 : cols tn*4..+3

    const float* hrow;
    if (GATHER) {
        int b = borig[r0 + lm];
        hrow = (b >= 0) ? &in[(size_t)b * K] : (const float*)0;
    } else {
        hrow = &in[(size_t)(r0 + lm) * K];   // pad rows hold garbage; harmless
    }

    float acc[4][4];
    #pragma unroll
    for (int i = 0; i < 4; ++i)
        #pragma unroll
        for (int j = 0; j < 4; ++j) acc[i][j] = 0.f;

    for (int k0 = 0; k0 < K; k0 += 16) {
        float4 hv = make_float4(0.f, 0.f, 0.f, 0.f);
        if (!GATHER || hrow) hv = *(const float4*)&hrow[k0 + lq * 4];
        float4 wv = *(const float4*)&w[(size_t)(k0 + wk) * DOUT + cb + wc];
        __syncthreads();
        hs[lq * 4 + 0][lm] = hv.x;
        hs[lq * 4 + 1][lm] = hv.y;
        hs[lq * 4 + 2][lm] = hv.z;
        hs[lq * 4 + 3][lm] = hv.w;
        *(float4*)&wt[wk][wc] = wv;
        __syncthreads();
        #pragma unroll
        for (int kk = 0; kk < 16; ++kk) {
            float4 a  = *(const float4*)&hs[kk][tm * 4];
            float4 bf = *(const float4*)&wt[kk][tn * 4];
            acc[0][0] = fmaf(a.x, bf.x, acc[0][0]);
            acc[0][1] = fmaf(a.x, bf.y, acc[0][1]);
            acc[0][2] = fmaf(a.x, bf.z, acc[0][2]);
            acc[0][3] = fmaf(a.x, bf.w, acc[0][3]);
            acc[1][0] = fmaf(a.y, bf.x, acc[1][0]);
            acc[1][1] = fmaf(a.y, bf.y, acc[1][1]);
            acc[1][2] = fmaf(a.y, bf.z, acc[1][2]);
            acc[1][3] = fmaf(a.y, bf.w, acc[1][3]);
            acc[2][0] = fmaf(a.z, bf.x, acc[2][0]);
            acc[2][1] = fmaf(a.z, bf.y, acc[2][1]);
            acc[2][2] = fmaf(a.z, bf.z, acc[2][2]);
            acc[2][3] = fmaf(a.z, bf.w, acc[2][3]);
            acc[3][0] = fmaf(a.w, bf.x, acc[3][0]);
            acc[3][1] = fmaf(a.w, bf.y, acc[3][1]);
            acc[3][2] = fmaf(a.w, bf.z, acc[3][2]);
            acc[3][3] = fmaf(a.w, bf.w, acc[3][3]);
        }
    }

    float4 bv = *(const float4*)&bias[cb + tn * 4];
    #pragma unroll
    for (int i = 0; i < 4; ++i) {
        float o[4];
        o[0] = fmaxf(acc[i][0] + bv.x, 0.f);
        o[1] = fmaxf(acc[i][1] + bv.y, 0.f);
        o[2] = fmaxf(acc[i][2] + bv.z, 0.f);
        o[3] = fmaxf(acc[i][3] + bv.w, 0.f);
        if (SPLIT) {
            // element (row, k): frag addr = ((by*32+kk)*3+limb)*2048 + m*512
            //                               + (lg*16 + l15)*8 + j   [shorts]
            int row = r0 + tm * 4 + i;
            int by_ = row >> 6, rl = row & 63;
            int mfr = rl >> 4, p15 = rl & 15;
            int kt  = cb + tn * 4;           // 4 consecutive k, same lg group
            int kk  = kt >> 5, lgk = (kt >> 3) & 3, j0 = kt & 7;
            size_t base = (size_t)(by_ * 32 + kk) * 6144 + (size_t)mfr * 512
                        + (size_t)(lgk * 16 + p15) * 8 + j0;
            ushort4 s0, s1, s2;
            unsigned short* q0[4] = {&s0.x, &s0.y, &s0.z, &s0.w};
            unsigned short* q1[4] = {&s1.x, &s1.y, &s1.z, &s1.w};
            unsigned short* q2[4] = {&s2.x, &s2.y, &s2.z, &s2.w};
            #pragma unroll
            for (int j = 0; j < 4; ++j) {
                unsigned short a0 = f2bf(o[j]);
                float r1v = o[j] - bf2f(a0);
                unsigned short a1 = f2bf(r1v);
                float r2v = r1v - bf2f(a1);
                *q0[j] = a0; *q1[j] = a1; *q2[j] = f2bf(r2v);
            }
            *(ushort4*)&hbA[base]        = s0;
            *(ushort4*)&hbA[base + 2048] = s1;
            *(ushort4*)&hbA[base + 4096] = s2;
        } else {
            float4 ov;
            ov.x = o[0]; ov.y = o[1]; ov.z = o[2]; ov.w = o[3];
            *(float4*)&out[(size_t)(r0 + tm * 4 + i) * DOUT + cb + tn * 4] = ov;
        }
    }
}

// ---------------- kernel 2: bf16x3 MFMA DIFF-GEMM, ONE WAVE PER BLOCK --------
// Across R6-R11 all zero-LDS variants sat at OccupancyPercent ~31% (~10
// waves/CU) despite VGPR 72 permitting ~28 -> too few outstanding loads to
// use HBM (1.2 TB/s of 6.3 achievable); k2 is BW-limited at 520 MB fetch.
// Waves are fully independent (no LDS/barriers/cross-wave data), so launch
// 64-thread blocks: tiny blocks pack to the VGPR limit (~28 waves/CU),
// ~2.8x concurrency. Kernel body = R7's proven 2-deep pipeline, unchanged.
// Decode keeps XCD col-ownership: wgid%8 = bx%8 (R4-proven L2 mechanism).
__global__ __launch_bounds__(64) void k2_mfma(
    const unsigned short* __restrict__ hbA,
    const float* __restrict__ bw3, const float* __restrict__ bb3,
    const float* __restrict__ sw3, const float* __restrict__ sb3,
    const float* __restrict__ gum,
    const int* __restrict__ meta, const int* __restrict__ borig,
    unsigned char* __restrict__ bits) {
    int lane = threadIdx.x;             // 0..63
    int wgid = blockIdx.x;              // 0..9215
    int xr = wgid & 7;                  // XCD slot
    int z  = wgid >> 3;                 // 0..1151
    int by = z % 9;                     // row tile 0..8
    int v  = z / 9;                     // 0..127
    int wid = v & 3;                    // wave slot 0..3 (diff cols wid*32..+31)
    int q   = v >> 2;                   // col chunk 0..31
    int bx  = q * 8 + xr;               // col tile 0..255
    if (bx >= 255) return;

    int r0 = by * 64;
    int db = bx * 128;                  // diff (e-pair) column base
    int S = meta[0];
    bool big = (r0 < S);
    const float* w3 = big ? bw3 : sw3;
    const float* b3 = big ? bb3 : sb3;

    int l15  = lane & 15;
    int lg   = lane >> 4;               // k-group 0..3

    int colg0 = db + wid * 32 + l15;    // this lane's n=0 diff column

    f32x4 acc[4][2];
    #pragma unroll
    for (int m = 0; m < 4; ++m)
        #pragma unroll
        for (int n = 0; n < 2; ++n) acc[m][n] = (f32x4)0.f;

    const unsigned short* ap0 = hbA + (size_t)(by * 32) * 6144 + (size_t)lane * 8;
    const float* wbase = w3 + (size_t)(lg * 8) * OUTCOLS + 2 * (size_t)colg0;

#define LOADB(BUF, KK) do {                                                     \
    const float* wp_ = wbase + (size_t)(KK) * 32 * OUTCOLS;                     \
    _Pragma("unroll")                                                           \
    for (int n_ = 0; n_ < 2; ++n_) {                                            \
        _Pragma("unroll")                                                       \
        for (int j_ = 0; j_ < 8; ++j_)                                          \
            BUF[n_ * 8 + j_] = *(const float2*)(wp_ + (size_t)j_ * OUTCOLS      \
                                                + n_ * 32);                     \
    }                                                                           \
} while (0)

#define STEP(BUF, KK) do {                                                      \
    const unsigned short* ap_ = ap0 + (size_t)(KK) * 6144;                      \
    bf16x8 af_[3][4];                                                           \
    _Pragma("unroll")                                                           \
    for (int l_ = 0; l_ < 3; ++l_)                                              \
        _Pragma("unroll")                                                       \
        for (int m_ = 0; m_ < 4; ++m_)                                          \
            af_[l_][m_] = *(const bf16x8*)(ap_ + l_ * 2048 + m_ * 512);         \
    _Pragma("unroll")                                                           \
    for (int n_ = 0; n_ < 2; ++n_) {                                            \
        u32x4 f0_, f1_, f2_;                                                    \
        _Pragma("unroll")                                                       \
        for (int w_ = 0; w_ < 4; ++w_) {                                        \
            float dA_ = BUF[n_ * 8 + 2 * w_].x     - BUF[n_ * 8 + 2 * w_].y;    \
            float dB_ = BUF[n_ * 8 + 2 * w_ + 1].x - BUF[n_ * 8 + 2 * w_ + 1].y;\
            unsigned short aL_ = f2bf(dA_), aH_ = f2bf(dB_);                    \
            f0_[w_] = (unsigned int)aL_ | ((unsigned int)aH_ << 16);            \
            float rA_ = dA_ - bf2f(aL_), rB_ = dB_ - bf2f(aH_);                 \
            unsigned short bL_ = f2bf(rA_), bH_ = f2bf(rB_);                    \
            f1_[w_] = (unsigned int)bL_ | ((unsigned int)bH_ << 16);            \
            float sA_ = rA_ - bf2f(bL_), sB_ = rB_ - bf2f(bH_);                 \
            f2_[w_] = (unsigned int)f2bf(sA_) | ((unsigned int)f2bf(sB_) << 16);\
        }                                                                       \
        bf16x8 b0_ = __builtin_bit_cast(bf16x8, f0_);                           \
        bf16x8 b1_ = __builtin_bit_cast(bf16x8, f1_);                           \
        bf16x8 b2_ = __builtin_bit_cast(bf16x8, f2_);                           \
        _Pragma("unroll")                                                       \
        for (int m_ = 0; m_ < 4; ++m_) {                                        \
            f32x4 c_ = acc[m_][n_];                                             \
            c_ = __builtin_amdgcn_mfma_f32_16x16x32_bf16(af_[0][m_], b0_, c_, 0, 0, 0); \
            c_ = __builtin_amdgcn_mfma_f32_16x16x32_bf16(af_[0][m_], b1_, c_, 0, 0, 0); \
            c_ = __builtin_amdgcn_mfma_f32_16x16x32_bf16(af_[1][m_], b0_, c_, 0, 0, 0); \
            c_ = __builtin_amdgcn_mfma_f32_16x16x32_bf16(af_[1][m_], b1_, c_, 0, 0, 0); \
            c_ = __builtin_amdgcn_mfma_f32_16x16x32_bf16(af_[0][m_], b2_, c_, 0, 0, 0); \
            c_ = __builtin_amdgcn_mfma_f32_16x16x32_bf16(af_[2][m_], b0_, c_, 0, 0, 0); \
            acc[m_][n_] = c_;                                                   \
        }                                                                       \
    }                                                                           \
} while (0)

    float2 brE[16], brO[16];
    LOADB(brE, 0);
    for (int ki = 0; ki < 16; ++ki) {
        int ke = ki * 2;
        LOADB(brO, ke + 1);             // prefetch odd step
        STEP(brE, ke);
        LOADB(brE, (ki < 15) ? ke + 2 : 31);   // prefetch next even step
        STEP(brO, ke + 1);
    }
#undef LOADB
#undef STEP

    // ---- epilogue: bias-diff + gumbel-diff, compare, store bit bytes ----
    #pragma unroll
    for (int n = 0; n < 2; ++n) {
        int colg = db + wid * 32 + n * 16 + l15;     // global e-pair index
        float2 bv = *(const float2*)&b3[2 * colg];
        float bd = bv.x - bv.y;
        #pragma unroll
        for (int m = 0; m < 4; ++m) {
            #pragma unroll
            for (int r = 0; r < 4; ++r) {
                int slot = r0 + m * 16 + lg * 4 + r;
                int b = borig[slot];
                if (b < 0) continue;
                float2 gv = *(const float2*)&gum[(size_t)b * OUTCOLS + 2 * colg];
                float g = acc[m][n][r] + bd + (gv.x - gv.y);
                bits[(size_t)b * E_PAIRS + colg] = (g >= 0.f) ? 1 : 0;
            }
        }
    }
}

// ---------------- kernel 3: tiled bit->fp32 expansion with LDS transpose ------
__global__ __launch_bounds__(256) void k3_expand(
    const unsigned char* __restrict__ bits, float* __restrict__ out) {
    __shared__ unsigned char L[64][68];   // stride 68 bytes
    int p = blockIdx.x;                   // 0..9 -> (ti,tj), ti<=tj
    int ti = (p >= 4) + (p >= 7) + (p >= 9);
    int off = (ti == 0) ? 0 : (ti == 1) ? 4 : (ti == 2) ? 7 : 9;
    int tj = ti + (p - off);
    int b = blockIdx.y;                   // 0..511
    int t = threadIdx.x;

    {
        int r = t >> 2;                   // 0..63
        int q = t & 3;                    // 0..3
        int i = ti * 64 + r;
        long base = (long)b * E_PAIRS + (long)i * (511 - i) / 2 - i - 1;
        int j0 = tj * 64 + q * 16;
        #pragma unroll
        for (int k = 0; k < 16; ++k) {
            int j = j0 + k;
            unsigned char v = (j > i) ? bits[base + j] : (unsigned char)0;
            L[r][q * 16 + k] = v;
        }
    }
    __syncthreads();

    int h  = t >> 4;                      // 0..15
    int w4 = (t & 15) * 4;                // col base, float4 granularity

    {
        #pragma unroll
        for (int rr = 0; rr < 4; ++rr) {
            int ii = rr * 16 + h;
            int i_ = ti * 64 + ii;
            float4 v;
            if (ti == tj) {
                int jj;
                jj = w4 + 0; v.x = (jj > ii) ? (float)L[ii][jj] : (jj < ii ? (float)L[jj][ii] : 0.f);
                jj = w4 + 1; v.y = (jj > ii) ? (float)L[ii][jj] : (jj < ii ? (float)L[jj][ii] : 0.f);
                jj = w4 + 2; v.z = (jj > ii) ? (float)L[ii][jj] : (jj < ii ? (float)L[jj][ii] : 0.f);
                jj = w4 + 3; v.w = (jj > ii) ? (float)L[ii][jj] : (jj < ii ? (float)L[jj][ii] : 0.f);
            } else {
                v.x = (float)L[ii][w4 + 0];
                v.y = (float)L[ii][w4 + 1];
                v.z = (float)L[ii][w4 + 2];
                v.w = (float)L[ii][w4 + 3];
            }
            size_t o = (((size_t)b * 256 + i_) * 256) + tj * 64 + w4;
            *(float4*)&out[o] = v;
        }
    }

    if (ti != tj) {
        #pragma unroll
        for (int rr = 0; rr < 4; ++rr) {
            int jj = rr * 16 + h;
            int j_ = tj * 64 + jj;
            float4 v;
            v.x = (float)L[w4 + 0][jj];
            v.y = (float)L[w4 + 1][jj];
            v.z = (float)L[w4 + 2][jj];
            v.w = (float)L[w4 + 3][jj];
            size_t o = (((size_t)b * 256 + j_) * 256) + ti * 64 + w4;
            *(float4*)&out[o] = v;
        }
    }
}

// -----------------------------------------------------------------------------
extern "C" void kernel_launch(void* const* d_in, const int* in_sizes, int n_in,
                              void* d_out, int out_size, void* d_ws, size_t ws_size,
                              hipStream_t stream) {
    const float* x   = (const float*)d_in[0];
    const float* gum = (const float*)d_in[1];
    const float* bw0 = (const float*)d_in[2];  const float* bb0 = (const float*)d_in[3];
    const float* sw0 = (const float*)d_in[4];  const float* sb0 = (const float*)d_in[5];
    const float* bw1 = (const float*)d_in[6];  const float* bb1 = (const float*)d_in[7];
    const float* sw1 = (const float*)d_in[8];  const float* sb1 = (const float*)d_in[9];
    const float* bw2 = (const float*)d_in[10]; const float* bb2 = (const float*)d_in[11];
    const float* sw2 = (const float*)d_in[12]; const float* sb2 = (const float*)d_in[13];
    const float* bw3 = (const float*)d_in[14]; const float* bb3 = (const float*)d_in[15];
    const float* sw3 = (const float*)d_in[16]; const float* sb3 = (const float*)d_in[17];

    char* ws = (char*)d_ws;
    int*   meta  = (int*)ws;                               // 64 B
    int*   borig = (int*)(ws + 64);                        // 576 ints
    float* act1  = (float*)(ws + 4096);                    // 576*256 fp32
    float* act2  = (float*)(ws + 593920);                  // 576*512 fp32
    unsigned short* hbA = (unsigned short*)(ws + 1773568); // 576*1024*3 bf16 frag-order
    unsigned char* bits = (unsigned char*)(ws + 5312512);  // 512*32640 bytes
    float* out = (float*)d_out;                            // total ws use ~22.0 MB

    k0_sort<<<1, SLOTS, 0, stream>>>(x, meta, borig);
    k1_gemm<true,  COND, D1, false><<<dim3(9, D1 / 64), 256, 0, stream>>>(
        x,    bw0, bb0, sw0, sb0, meta, borig, act1, 0);
    k1_gemm<false, D1,   D2, false><<<dim3(9, D2 / 64), 256, 0, stream>>>(
        act1, bw1, bb1, sw1, sb1, meta, borig, act2, 0);
    k1_gemm<false, D2,   D3, true><<<dim3(9, D3 / 64), 256, 0, stream>>>(
        act2, bw2, bb2, sw2, sb2, meta, borig, (float*)0, hbA);
    k2_mfma<<<9216, 64, 0, stream>>>(hbA, bw3, bb3, sw3, sb3, gum,
                                     meta, borig, bits);
    k3_expand<<<dim3(10, BATCH), 256, 0, stream>>>(bits, out);
}